// Round 17
// baseline (190.965 us; speedup 1.0000x reference)
//
#include <hip/hip_runtime.h>

// SSIM3D, (4,1,128,128,128) fp32, separable 11-tap Gaussian, scalar mean out.
//
// R23: STATIC-SLOT PREFETCH (kill the rotation-wait). R22 post-mortem:
// z-inner layout moved B 0us -> B never pattern-bound. New mechanism found:
// every step ends with a register ROTATION (P0=P1..P5=N / h1=h2;h2=Rn) that
// READS the just-issued load's destination -> forces s_waitcnt vmcnt in the
// SAME step the load issues, destroying the prefetch slack at every
// unroll-boundary. (Explains why depth 2/4/6 all measured identical.)
// Fix: fully unroll all steps; modular slot files with compile-time
// indices -- B: P[6][4], step t consumes slot t%6 (load from t-6 = 6 steps
// of slack) then reloads it for t+6; A: R[4] float4, step t LDS-writes slot
// (t+2)&3, loads row t+4 into slot t&3. Zero copies. Math/order identical
// to R22 (absmax 0.0 x8).
// Invariants: A WRITE_SIZE == 131072 KB, VGPR <= 128, absmax 0.
// Decision: total ~170 -> copies were already renamed -> plateau structural.

#define SLICE (128*128)        // 16384
#define S  (128*SLICE)         // 2097152 per field per batch
#define FR  512                // floats per (y,z) field-row: [4 f][128 x]
#define C1_ 0.0001f
#define C2_ 0.0009f

__device__ __forceinline__ void make_g_s(float* gs) {
    float g[11]; float s = 0.f;
#pragma unroll
    for (int i = 0; i < 11; ++i) {
        float d = (float)(i - 5);
        g[i] = __expf(-d * d / 4.5f);
        s += g[i];
    }
    float inv = 1.f / s;
#pragma unroll
    for (int i = 0; i < 11; ++i)
        gs[i] = __int_as_float(__builtin_amdgcn_readfirstlane(
                    __float_as_int(g[i] * inv)));
}

// ---------------- Kernel A: x-conv + y-conv, walk y ----------------
// grid: 2048 blocks of 256 threads = 4 independent waves. Wave pair
// p = w>>1 owns unit idx = blockIdx.x*2 + p (decoded n, z, yc); within the
// pair, wave w&1 owns x-half (x = (w&1)*64 + lane). Each wave stages the
// FULL row pair into its private LDS ring (lanes 0-31 img1, 32-63 img2).
// Thread walks 16 y outputs (26 steps, fully unrolled).
// Ring: 4 slots x (img1 row | img2 row), rows padded to 160 floats (data at
// dwords [8..135], zeros outside): maskless 11-tap.
// Static-slot pipeline: R[4] float4; step t: LDS-write row t+2 from slot
// (t+2)&3 (loaded at t-2), issue load row t+4 into slot t&3. No copies.
#define RB    160              // dwords per padded row
#define RSLOT (2*RB)           // 320 dwords per ring slot
#define WRING (4*RSLOT)        // 1280 dwords per wave ring (4 slots) = 5 KiB

#define STEPA(T_, TM_, J0_, J1_, STORE_, OKC_) do {                           \
    const int T__ = (T_);                                                     \
    int sp__ = T__ + 4; if (sp__ > 25) sp__ = 25;                             \
    int rowc__ = min(max(y0 + sp__ - 5, 0), 127);                             \
    R[(T_) & 3] = *(const float4*)(src + (size_t)rowc__ * 128);               \
    if (OKC_) {                                                               \
        const float* rp__ = p_rd + ((T_) & 3) * RSLOT;                        \
        float u1__ = 0.f, u2__ = 0.f, ss__ = 0.f, a12__ = 0.f;                \
        _Pragma("unroll")                                                     \
        for (int j = 0; j < 6; ++j) {                                         \
            float2 va__ = *(const float2*)(rp__ + 2 * j);                     \
            float2 vb__ = *(const float2*)(rp__ + RB + 2 * j);                \
            {                                                                 \
                float wj__ = w12[2 * j];                                      \
                float ta__ = wj__ * va__.x, tb__ = wj__ * vb__.x;             \
                u1__ += ta__; u2__ += tb__;                                   \
                ss__  = fmaf(ta__, va__.x, ss__);                             \
                ss__  = fmaf(tb__, vb__.x, ss__);                             \
                a12__ = fmaf(ta__, vb__.x, a12__);                            \
            }                                                                 \
            {                                                                 \
                float wj__ = w12[2 * j + 1];                                  \
                float ta__ = wj__ * va__.y, tb__ = wj__ * vb__.y;             \
                u1__ += ta__; u2__ += tb__;                                   \
                ss__  = fmaf(ta__, va__.y, ss__);                             \
                ss__  = fmaf(tb__, vb__.y, ss__);                             \
                a12__ = fmaf(ta__, vb__.y, a12__);                            \
            }                                                                 \
        }                                                                     \
        _Pragma("unroll")                                                     \
        for (int j = (J0_); j <= (J1_); ++j) {                                \
            const int sl__ = ((TM_) + j + 1) % 11;                            \
            float wy__ = gs[10 - j];                                          \
            acc[0][sl__] = fmaf(wy__, u1__,  acc[0][sl__]);                   \
            acc[1][sl__] = fmaf(wy__, u2__,  acc[1][sl__]);                   \
            acc[2][sl__] = fmaf(wy__, ss__,  acc[2][sl__]);                   \
            acc[3][sl__] = fmaf(wy__, a12__, acc[3][sl__]);                   \
        }                                                                     \
    }                                                                         \
    /* stage row T+2 (loaded at T-2, slot (T+2)&3 != T&3) */                  \
    *(float4*)(p_wr + (((T_) + 2) & 3) * RSLOT) = R[((T_) + 2) & 3];          \
    if (STORE_) {                                                             \
        size_t wo__ = (size_t)(y0 + T__ - 10) * (128 * FR);                   \
        const int es__ = ((TM_) + 1) % 11;                                    \
        _Pragma("unroll")                                                     \
        for (int f = 0; f < 4; ++f) {                                         \
            fb[wo__ + f * 128] = acc[f][es__];                                \
            acc[f][es__] = 0.f;                                               \
        }                                                                     \
    }                                                                         \
} while (0)

__global__ __launch_bounds__(256, 1)
void ssimA(const float* __restrict__ img1, const float* __restrict__ img2,
           float* __restrict__ fields) {
    __shared__ __align__(16) float ring[4 * WRING];   // 20 KiB (4 waves)
    float gs[11]; make_g_s(gs);
    const int tid = threadIdx.x;
    const int w = tid >> 6, l = tid & 63;      // wave 0..3, lane 0..63
    const int idx = blockIdx.x * 2 + (w >> 1); // work unit 0..4095
    const int x = ((w & 1) << 6) + l;          // output column 0..127
    const int yc = idx & 7, z = (idx >> 3) & 127, n = idx >> 10;
    const int y0 = yc * 16;
    // lanes 0-31 stage the img1 row (float4 each), lanes 32-63 the img2 row
    const float* src = (l < 32 ? img1 : img2)
                     + (size_t)n * S + (size_t)z * SLICE + 4 * (l & 31);
    // z-inner layout: element (n,y,z,f,x) at ((n*128+y)*128+z)*FR + f*128+x.
    float* fb = fields + ((size_t)n * 128 * 128 + z) * FR + x;

    // per-parity 12-tap weights over the aligned window [e, e+11],
    // e = (x-5)&~1, p = (x-5)&1; tap k has weight g[k-p] (0 outside 0..10).
    const int p = (x - 5) & 1;
    const int e = (x - 5) - p;                 // even, in [-6, 122]
    float w12[12];
#pragma unroll
    for (int k = 0; k < 12; ++k) {
        float we = (k <= 10) ? gs[k] : 0.f;            // p == 0
        float wo = (k >= 1) ? gs[k - 1] : 0.f;         // p == 1
        w12[k] = p ? wo : we;
    }

    float* wring = ring + w * WRING;           // private per-wave ring
    float* p_rd = wring + (8 + e);             // aligned window base (8B)
    float* p_wr = wring + ((l < 32) ? 0 : RB) + 8 + 4 * (l & 31);

    // zero whole ring once: pads stay zero forever (x-boundary = free)
    for (int i = l; i < WRING; i += 64) wring[i] = 0.f;

    float acc[4][11];
#pragma unroll
    for (int f = 0; f < 4; ++f)
#pragma unroll
        for (int s2 = 0; s2 < 11; ++s2) acc[f][s2] = 0.f;

    // prologue: LDS slots 0,1 <- rows 0,1; R[2],R[3] <- rows 2,3
    float4 R[4];
    {
        int r0 = min(max(y0 - 5, 0), 127);
        int r1 = min(max(y0 - 4, 0), 127);
        int r2 = min(max(y0 - 3, 0), 127);
        int r3 = min(max(y0 - 2, 0), 127);
        float4 R0 = *(const float4*)(src + (size_t)r0 * 128);
        float4 R1 = *(const float4*)(src + (size_t)r1 * 128);
        R[2]      = *(const float4*)(src + (size_t)r2 * 128);
        R[3]      = *(const float4*)(src + (size_t)r3 * 128);
        *(float4*)(p_wr)         = R0;         // LDS slot 0
        *(float4*)(p_wr + RSLOT) = R1;         // LDS slot 1
    }

    // head: t = 0..9 (partial y-window, row may be < 0; no stores)
#pragma unroll
    for (int t = 0; t < 10; ++t)
        STEPA(t, t, 10 - t, 10, false, (y0 + t - 5 >= 0));
    // mid: t = 10..15 -- full window, store every step
#pragma unroll
    for (int t = 10; t < 16; ++t)
        STEPA(t, t % 11, 0, 10, true, true);
    // drain: t = 16..25 (tail taps; row may be > 127 only at yc=7; store)
#pragma unroll
    for (int t = 16; t < 26; ++t)
        STEPA(t, t % 11, 0, 25 - t, true, (y0 + t - 5 < 128));
}

// ---------------- Kernel B: z-conv + map + reduce, walk z ----------------
// grid: 4n * 64y2 * 4zc = 1024 blocks of 256 threads (4 waves).
// Thread owns (x = tid&127, y = 2*y2 + (tid>>7)); walks 32 z outputs,
// FULLY UNROLLED (42 static steps). Static-slot pipeline P[6][4]: step t
// consumes slot t%6 (loaded at t-6 -> 6 steps of vmcnt slack), then
// reloads that slot for step t+6. No rotation copies. Z-inner layout:
// sequential 2 KB steps. Batches reversed (L3 hits).
#define STEPB(T_, TM_, SL_, J0_, J1_, STORE_, OKC_) do {                      \
    const int T__ = (T_);                                                     \
    /* consume slot SL_ (vmcnt waits for the 6-step-old load) */              \
    float c0__ = P[SL_][0], c1__ = P[SL_][1];                                 \
    float c2__ = P[SL_][2], c3__ = P[SL_][3];                                 \
    /* refill slot SL_ for step T+6 (issued early, 6 steps of slack) */       \
    {                                                                         \
        int sp__ = T__ + 6; if (sp__ > 41) sp__ = 41;                         \
        size_t off__ = (size_t)min(max(z0 + sp__ - 5, 0), 127) * FR;          \
        P[SL_][0] = base[off__];                                              \
        P[SL_][1] = base[off__ + 128];                                        \
        P[SL_][2] = base[off__ + 256];                                        \
        P[SL_][3] = base[off__ + 384];                                        \
    }                                                                         \
    if (OKC_) {                                                               \
        _Pragma("unroll")                                                     \
        for (int j = (J0_); j <= (J1_); ++j) {                                \
            const int sl__ = ((TM_) + j + 1) % 11;                            \
            float wz__ = gs[10 - j];                                          \
            acc[0][sl__] = fmaf(wz__, c0__, acc[0][sl__]);                    \
            acc[1][sl__] = fmaf(wz__, c1__, acc[1][sl__]);                    \
            acc[2][sl__] = fmaf(wz__, c2__, acc[2][sl__]);                    \
            acc[3][sl__] = fmaf(wz__, c3__, acc[3][sl__]);                    \
        }                                                                     \
    }                                                                         \
    if (STORE_) {                                                             \
        const int es__ = ((TM_) + 1) % 11;                                    \
        float m1__ = acc[0][es__], m2__ = acc[1][es__];                       \
        float ps__ = acc[2][es__], p12__ = acc[3][es__];                      \
        float m1s__ = m1__ * m1__, m2s__ = m2__ * m2__, m12__ = m1__ * m2__;  \
        float v12__ = ps__ - m1s__ - m2s__;     /* sigma1^2 + sigma2^2 */     \
        float cv__  = p12__ - m12__;            /* sigma12 */                 \
        float num__ = (2.f * m12__ + C1_) * (2.f * cv__ + C2_);               \
        float den__ = (m1s__ + m2s__ + C1_) * (v12__ + C2_);                  \
        sum += num__ / den__;                                                 \
        _Pragma("unroll")                                                     \
        for (int f = 0; f < 4; ++f) acc[f][es__] = 0.f;                       \
    }                                                                         \
} while (0)

__global__ __launch_bounds__(256, 1)
void ssimB(const float* __restrict__ fields, float* __restrict__ partials) {
    float gs[11]; make_g_s(gs);
    const int tid = threadIdx.x;
    const int x = tid & 127, yr = tid >> 7;
    const int b = blockIdx.x;
    const int zc = b & 3, y2 = (b >> 2) & 63;
    const int n = 3 - (b >> 8);                 // reverse batches (L3 hits)
    const int y = y2 * 2 + yr;
    const int z0 = zc * 32;
    const float* base = fields + ((size_t)n * 128 + y) * 128 * FR + x;

    float acc[4][11];
#pragma unroll
    for (int f = 0; f < 4; ++f)
#pragma unroll
        for (int s2 = 0; s2 < 11; ++s2) acc[f][s2] = 0.f;

    float sum = 0.f;

    // prologue: slots 0..5 <- slices for steps 0..5 (z0-5 .. z0)
    float P[6][4];
#pragma unroll
    for (int t = 0; t < 6; ++t) {
        size_t o__ = (size_t)min(max(z0 + t - 5, 0), 127) * FR;
#pragma unroll
        for (int f = 0; f < 4; ++f) P[t][f] = base[o__ + f * 128];
    }

    // head: t = 0..9  (all step indices compile-time; slots t%6 static)
#pragma unroll
    for (int t = 0; t < 10; ++t)
        STEPB(t, t, t % 6, 10 - t, 10, false, (z0 + t - 5 >= 0));
    // steady: t = 10..31 -- fully unrolled, branch-free
#pragma unroll
    for (int t = 10; t < 32; ++t)
        STEPB(t, t % 11, t % 6, 0, 10, true, true);
    // drain: t = 32..41
#pragma unroll
    for (int t = 32; t < 42; ++t)
        STEPB(t, t % 11, t % 6, 0, 41 - t, true, (z0 + t - 5 < 128));

    // 4-wave reduce
#pragma unroll
    for (int o = 32; o > 0; o >>= 1) sum += __shfl_down(sum, o, 64);
    __shared__ float ws4[4];
    if ((tid & 63) == 0) ws4[tid >> 6] = sum;
    __syncthreads();
    if (tid == 0) partials[blockIdx.x] = ws4[0] + ws4[1] + ws4[2] + ws4[3];
}

// ---------------- final reduce ----------------
__global__ void ssim_final(const float* __restrict__ partial, int n,
                           float* __restrict__ out, double inv_count) {
    int tid = threadIdx.x;
    double s = 0.0;
    for (int i = tid; i < n; i += 256) s += (double)partial[i];
#pragma unroll
    for (int o = 32; o > 0; o >>= 1) s += __shfl_down(s, o, 64);
    __shared__ double wsum[4];
    int lane = tid & 63, wid = tid >> 6;
    if (lane == 0) wsum[wid] = s;
    __syncthreads();
    if (tid == 0)
        out[0] = (float)((wsum[0] + wsum[1] + wsum[2] + wsum[3]) * inv_count);
}

extern "C" void kernel_launch(void* const* d_in, const int* in_sizes, int n_in,
                              void* d_out, int out_size, void* d_ws, size_t ws_size,
                              hipStream_t stream) {
    const float* img1 = (const float*)d_in[0];
    const float* img2 = (const float*)d_in[1];
    float* out = (float*)d_out;

    float* fields   = (float*)d_ws;                    // 16*S floats (134 MB)
    float* partials = fields + 16 * (size_t)S;         // 1024 floats

    ssimA<<<2048, 256, 0, stream>>>(img1, img2, fields);
    ssimB<<<1024, 256, 0, stream>>>(fields, partials);
    ssim_final<<<1, 256, 0, stream>>>(partials, 1024, out,
                                      1.0 / ((double)S * 4));
}